// Round 1
// baseline (959.047 us; speedup 1.0000x reference)
//
#include <hip/hip_runtime.h>
#include <hip/hip_bf16.h>

// ---------------- degree + count ----------------
__global__ void k_deg_count(const int* __restrict__ row, const int* __restrict__ col,
                            const float* __restrict__ ew, int E, int e2,
                            float* __restrict__ deg, int* __restrict__ cnt) {
    int e = blockIdx.x * blockDim.x + threadIdx.x;
    if (e >= e2) return;
    int dst; float w;
    if (e < E) { dst = col[e]; w = ew[e]; }
    else       { dst = e - E; w = 1.0f; }
    atomicAdd(&deg[dst], w);
    atomicAdd(&cnt[dst], 1);
}

__global__ void k_dinv(float* __restrict__ deg, int n) {
    int i = blockIdx.x * blockDim.x + threadIdx.x;
    if (i >= n) return;
    float d = deg[i];
    deg[i] = (d > 0.0f) ? rsqrtf(d) : 0.0f;
}

// ---------------- exclusive scan (3-kernel hierarchical) ----------------
#define SCAN_T 256
#define SCAN_E 1024

__global__ void k_scan_a(const int* __restrict__ cnt, int n,
                         int* __restrict__ rowptr, int* __restrict__ bsum) {
    __shared__ int s[SCAN_T];
    int t = threadIdx.x, b = blockIdx.x;
    int base = b * SCAN_E + t * 4;
    int c0 = (base + 0 < n) ? cnt[base + 0] : 0;
    int c1 = (base + 1 < n) ? cnt[base + 1] : 0;
    int c2 = (base + 2 < n) ? cnt[base + 2] : 0;
    int c3 = (base + 3 < n) ? cnt[base + 3] : 0;
    int tsum = c0 + c1 + c2 + c3;
    s[t] = tsum; __syncthreads();
    for (int off = 1; off < SCAN_T; off <<= 1) {
        int v = (t >= off) ? s[t - off] : 0;
        __syncthreads();
        s[t] += v;
        __syncthreads();
    }
    int excl = s[t] - tsum;
    if (base + 0 < n) rowptr[base + 0] = excl;
    if (base + 1 < n) rowptr[base + 1] = excl + c0;
    if (base + 2 < n) rowptr[base + 2] = excl + c0 + c1;
    if (base + 3 < n) rowptr[base + 3] = excl + c0 + c1 + c2;
    if (t == 0) bsum[b] = s[SCAN_T - 1];
}

__global__ void k_scan_b(int* __restrict__ bsum, int nb) {
    __shared__ int s[128];
    int t = threadIdx.x;
    int v = (t < nb) ? bsum[t] : 0;
    s[t] = v; __syncthreads();
    for (int off = 1; off < 128; off <<= 1) {
        int u = (t >= off) ? s[t - off] : 0;
        __syncthreads();
        s[t] += u;
        __syncthreads();
    }
    if (t < nb) bsum[t] = s[t] - v;   // exclusive
}

__global__ void k_scan_c(int* __restrict__ rowptr, const int* __restrict__ bsum,
                         int n, int total) {
    int i = blockIdx.x * blockDim.x + threadIdx.x;
    if (i < n) rowptr[i] += bsum[i / SCAN_E];
    if (i == 0) rowptr[n] = total;
}

// ---------------- CSR fill (grouped by destination) ----------------
__global__ void k_fill(const int* __restrict__ row, const int* __restrict__ col,
                       const float* __restrict__ ew, const float* __restrict__ dinv,
                       const int* __restrict__ rowptr, int* __restrict__ fill,
                       int E, int e2, int* __restrict__ csr_src, float* __restrict__ csr_w) {
    int e = blockIdx.x * blockDim.x + threadIdx.x;
    if (e >= e2) return;
    int src, dst; float w;
    if (e < E) { src = row[e]; dst = col[e]; w = ew[e]; }
    else       { src = dst = e - E; w = 1.0f; }
    int p = rowptr[dst] + atomicAdd(&fill[dst], 1);
    csr_src[p] = src;
    csr_w[p] = dinv[src] * w * dinv[dst];
}

// ---------------- fp32 GEMM: O[n x 128] = H[n x 128] @ W[128 x 128] ----------------
__global__ __launch_bounds__(256) void k_gemm(const float* __restrict__ H,
                                              const float* __restrict__ W,
                                              float* __restrict__ O, int n) {
    __shared__ float Hs[64][33];    // pad 33: 2-way max on scalar reads
    __shared__ float Ws[32][132];   // pad 132: keeps float4 alignment (528B rows)
    int t = threadIdx.x;
    int tx = t & 15, ty = t >> 4;
    int rowBase = blockIdx.x * 64;
    float acc[4][8] = {};
    for (int kk = 0; kk < 128; kk += 32) {
        // stage H tile 64x32
#pragma unroll
        for (int i = 0; i < 2; ++i) {
            int f4 = t + i * 256;            // 512 float4s
            int r = f4 >> 3, c = (f4 & 7) * 4;
            int gr = rowBase + r;
            float4 v = make_float4(0.f, 0.f, 0.f, 0.f);
            if (gr < n) v = *(const float4*)&H[gr * 128 + kk + c];
            Hs[r][c + 0] = v.x; Hs[r][c + 1] = v.y;
            Hs[r][c + 2] = v.z; Hs[r][c + 3] = v.w;
        }
        // stage W tile 32x128
#pragma unroll
        for (int i = 0; i < 4; ++i) {
            int f4 = t + i * 256;            // 1024 float4s
            int kr = f4 >> 5, c = (f4 & 31) * 4;
            float4 v = *(const float4*)&W[(kk + kr) * 128 + c];
            *(float4*)&Ws[kr][c] = v;
        }
        __syncthreads();
#pragma unroll
        for (int k = 0; k < 32; ++k) {
            float4 w0 = *(const float4*)&Ws[k][tx * 8];
            float4 w1 = *(const float4*)&Ws[k][tx * 8 + 4];
#pragma unroll
            for (int i = 0; i < 4; ++i) {
                float h = Hs[ty * 4 + i][k];
                acc[i][0] += h * w0.x; acc[i][1] += h * w0.y;
                acc[i][2] += h * w0.z; acc[i][3] += h * w0.w;
                acc[i][4] += h * w1.x; acc[i][5] += h * w1.y;
                acc[i][6] += h * w1.z; acc[i][7] += h * w1.w;
            }
        }
        __syncthreads();
    }
#pragma unroll
    for (int i = 0; i < 4; ++i) {
        int gr = rowBase + ty * 4 + i;
        if (gr < n) {
            *(float4*)&O[gr * 128 + tx * 8] =
                make_float4(acc[i][0], acc[i][1], acc[i][2], acc[i][3]);
            *(float4*)&O[gr * 128 + tx * 8 + 4] =
                make_float4(acc[i][4], acc[i][5], acc[i][6], acc[i][7]);
        }
    }
}

// ---------------- aggregation: out[dst] = sum_e w_e * Hw[src_e] + b (opt relu) ----------------
template<bool RELU>
__global__ void k_agg(const float* __restrict__ Hw, const int* __restrict__ rowptr,
                      const int* __restrict__ csr_src, const float* __restrict__ csr_w,
                      const float* __restrict__ bias, float* __restrict__ out, int n) {
    int node = blockIdx.x * 4 + (threadIdx.x >> 6);
    if (node >= n) return;
    int lane = threadIdx.x & 63;
    int s = rowptr[node], e = rowptr[node + 1];
    float ax = 0.f, ay = 0.f;
    for (int i = s; i < e; ++i) {
        int src = csr_src[i];
        float w = csr_w[i];
        float2 v = *(const float2*)&Hw[src * 128 + lane * 2];
        ax += v.x * w; ay += v.y * w;
    }
    float2 b = *(const float2*)&bias[lane * 2];
    ax += b.x; ay += b.y;
    if (RELU) { ax = fmaxf(ax, 0.f); ay = fmaxf(ay, 0.f); }
    float2 r; r.x = ax; r.y = ay;
    *(float2*)&out[node * 128 + lane * 2] = r;
}

// ---------------- fused mean-pool + final linear ----------------
__device__ __forceinline__ int lower_bound_i(const int* a, int n, int key) {
    int lo = 0, hi = n;
    while (lo < hi) { int mid = (lo + hi) >> 1; if (a[mid] < key) lo = mid + 1; else hi = mid; }
    return lo;
}

__global__ void k_pool(const float* __restrict__ H, const int* __restrict__ batch,
                       const float* __restrict__ Wlin, const float* __restrict__ blin,
                       float* __restrict__ out, int n) {
    int g = blockIdx.x;
    int start = lower_bound_i(batch, n, g);
    int end   = lower_bound_i(batch, n, g + 1);
    int t = threadIdx.x;
    int wid = t >> 6, lane = t & 63;
    float ax = 0.f, ay = 0.f;
    for (int i = start + wid; i < end; i += 4) {
        float2 v = *(const float2*)&H[i * 128 + lane * 2];
        ax += v.x; ay += v.y;
    }
    __shared__ float ws[4][128];
    __shared__ float hg[128];
    ws[wid][lane * 2] = ax; ws[wid][lane * 2 + 1] = ay;
    __syncthreads();
    int cnt = end - start;
    float inv = 1.0f / fmaxf((float)cnt, 1.0f);
    if (t < 128) hg[t] = (ws[0][t] + ws[1][t] + ws[2][t] + ws[3][t]) * inv;
    __syncthreads();
    if (t < 16) {
        float s = blin[t];
        for (int ch = 0; ch < 128; ++ch) s += hg[ch] * Wlin[ch * 16 + t];
        out[g * 16 + t] = s;
    }
}

// ---------------- host ----------------
extern "C" void kernel_launch(void* const* d_in, const int* in_sizes, int n_in,
                              void* d_out, int out_size, void* d_ws, size_t ws_size,
                              hipStream_t stream) {
    const float* x    = (const float*)d_in[0];
    const int*   ei   = (const int*)d_in[1];
    const float* ew   = (const float*)d_in[2];
    const int*   batch= (const int*)d_in[3];
    const float* W1   = (const float*)d_in[4];
    const float* b1   = (const float*)d_in[5];
    const float* W2   = (const float*)d_in[6];
    const float* b2   = (const float*)d_in[7];
    const float* W3   = (const float*)d_in[8];
    const float* b3   = (const float*)d_in[9];
    const float* Wlin = (const float*)d_in[10];
    const float* blin = (const float*)d_in[11];
    float* out = (float*)d_out;

    int n  = in_sizes[0] / 128;
    int E  = in_sizes[2];
    int e2 = E + n;
    int G  = out_size / 16;
    const int* row = ei;
    const int* col = ei + E;

    char* ws = (char*)d_ws;
    size_t off = 0;
    auto alloc = [&](size_t bytes) -> void* {
        void* p = ws + off;
        off = (off + bytes + 255) & ~255UL;
        return p;
    };
    float* bufA   = (float*)alloc((size_t)n * 128 * 4);
    float* bufB   = (float*)alloc((size_t)n * 128 * 4);
    float* deg    = (float*)alloc((size_t)n * 4);       // becomes dinv in-place
    int*   cnt    = (int*)  alloc((size_t)n * 4);       // reused as fill counters
    int*   rowptr = (int*)  alloc((size_t)(n + 1) * 4);
    int*   bsum   = (int*)  alloc(4096);
    int*   csr_src= (int*)  alloc((size_t)e2 * 4);
    float* csr_w  = (float*)alloc((size_t)e2 * 4);
    (void)ws_size;

    hipMemsetAsync(deg, 0, (size_t)n * 4, stream);
    hipMemsetAsync(cnt, 0, (size_t)n * 4, stream);

    int eb = (e2 + 255) / 256;
    k_deg_count<<<eb, 256, 0, stream>>>(row, col, ew, E, e2, deg, cnt);
    k_dinv<<<(n + 255) / 256, 256, 0, stream>>>(deg, n);

    int nbScan = (n + SCAN_E - 1) / SCAN_E;
    k_scan_a<<<nbScan, SCAN_T, 0, stream>>>(cnt, n, rowptr, bsum);
    k_scan_b<<<1, 128, 0, stream>>>(bsum, nbScan);
    k_scan_c<<<(n + 255) / 256, 256, 0, stream>>>(rowptr, bsum, n, e2);

    hipMemsetAsync(cnt, 0, (size_t)n * 4, stream);
    k_fill<<<eb, 256, 0, stream>>>(row, col, ew, deg, rowptr, cnt, E, e2, csr_src, csr_w);

    int gb = (n + 63) / 64;
    int ab = (n + 3) / 4;
    k_gemm<<<gb, 256, 0, stream>>>(x, W1, bufA, n);
    k_agg<true><<<ab, 256, 0, stream>>>(bufA, rowptr, csr_src, csr_w, b1, bufB, n);
    k_gemm<<<gb, 256, 0, stream>>>(bufB, W2, bufA, n);
    k_agg<true><<<ab, 256, 0, stream>>>(bufA, rowptr, csr_src, csr_w, b2, bufB, n);
    k_gemm<<<gb, 256, 0, stream>>>(bufB, W3, bufA, n);
    k_agg<false><<<ab, 256, 0, stream>>>(bufA, rowptr, csr_src, csr_w, b3, bufB, n);
    k_pool<<<G, 256, 0, stream>>>(bufB, batch, Wlin, blin, out, n);
}

// Round 2
// 649.054 us; speedup vs baseline: 1.4776x; 1.4776x over previous
//
#include <hip/hip_runtime.h>
#include <hip/hip_bf16.h>

typedef __attribute__((ext_vector_type(8))) unsigned short ushort8;

__device__ __forceinline__ unsigned short f2bf(float f) {
    unsigned u = __float_as_uint(f);
    unsigned r = (u + 0x7FFF + ((u >> 16) & 1)) >> 16;   // RNE
    return (unsigned short)r;
}

// ---------------- degree + count ----------------
__global__ void k_deg_count(const int* __restrict__ row, const int* __restrict__ col,
                            const float* __restrict__ ew, int E, int e2,
                            float* __restrict__ deg, int* __restrict__ cnt) {
    int e = blockIdx.x * blockDim.x + threadIdx.x;
    if (e >= e2) return;
    int dst; float w;
    if (e < E) { dst = col[e]; w = ew[e]; }
    else       { dst = e - E; w = 1.0f; }
    atomicAdd(&deg[dst], w);
    atomicAdd(&cnt[dst], 1);
}

__global__ void k_dinv(float* __restrict__ deg, int n) {
    int i = blockIdx.x * blockDim.x + threadIdx.x;
    if (i >= n) return;
    float d = deg[i];
    deg[i] = (d > 0.0f) ? rsqrtf(d) : 0.0f;
}

// ---------------- exclusive scan (3-kernel hierarchical) ----------------
#define SCAN_T 256
#define SCAN_E 1024

__global__ void k_scan_a(const int* __restrict__ cnt, int n,
                         int* __restrict__ rowptr, int* __restrict__ bsum) {
    __shared__ int s[SCAN_T];
    int t = threadIdx.x, b = blockIdx.x;
    int base = b * SCAN_E + t * 4;
    int c0 = (base + 0 < n) ? cnt[base + 0] : 0;
    int c1 = (base + 1 < n) ? cnt[base + 1] : 0;
    int c2 = (base + 2 < n) ? cnt[base + 2] : 0;
    int c3 = (base + 3 < n) ? cnt[base + 3] : 0;
    int tsum = c0 + c1 + c2 + c3;
    s[t] = tsum; __syncthreads();
    for (int off = 1; off < SCAN_T; off <<= 1) {
        int v = (t >= off) ? s[t - off] : 0;
        __syncthreads();
        s[t] += v;
        __syncthreads();
    }
    int excl = s[t] - tsum;
    if (base + 0 < n) rowptr[base + 0] = excl;
    if (base + 1 < n) rowptr[base + 1] = excl + c0;
    if (base + 2 < n) rowptr[base + 2] = excl + c0 + c1;
    if (base + 3 < n) rowptr[base + 3] = excl + c0 + c1 + c2;
    if (t == 0) bsum[b] = s[SCAN_T - 1];
}

__global__ void k_scan_b(int* __restrict__ bsum, int nb) {
    __shared__ int s[128];
    int t = threadIdx.x;
    int v = (t < nb) ? bsum[t] : 0;
    s[t] = v; __syncthreads();
    for (int off = 1; off < 128; off <<= 1) {
        int u = (t >= off) ? s[t - off] : 0;
        __syncthreads();
        s[t] += u;
        __syncthreads();
    }
    if (t < nb) bsum[t] = s[t] - v;   // exclusive
}

__global__ void k_scan_c(int* __restrict__ rowptr, const int* __restrict__ bsum,
                         int n, int total) {
    int i = blockIdx.x * blockDim.x + threadIdx.x;
    if (i < n) rowptr[i] += bsum[i / SCAN_E];
    if (i == 0) rowptr[n] = total;
}

// ---------------- CSR fill: interleaved (src, w) pairs grouped by destination ----------------
__global__ void k_fill(const int* __restrict__ row, const int* __restrict__ col,
                       const float* __restrict__ ew, const float* __restrict__ dinv,
                       const int* __restrict__ rowptr, int* __restrict__ fill,
                       int E, int e2, float2* __restrict__ csr) {
    int e = blockIdx.x * blockDim.x + threadIdx.x;
    if (e >= e2) return;
    int src, dst; float w;
    if (e < E) { src = row[e]; dst = col[e]; w = ew[e]; }
    else       { src = dst = e - E; w = 1.0f; }
    int p = rowptr[dst] + atomicAdd(&fill[dst], 1);
    float2 pr;
    pr.x = __int_as_float(src);
    pr.y = dinv[src] * w * dinv[dst];
    csr[p] = pr;
}

// ---------------- fp32 GEMM -> bf16 out: O[n x 128] = H[n x 128] @ W[128 x 128] ----------------
__global__ __launch_bounds__(256) void k_gemm(const float* __restrict__ H,
                                              const float* __restrict__ W,
                                              unsigned short* __restrict__ O, int n) {
    __shared__ float Hs[64][33];
    __shared__ float Ws[32][132];
    int t = threadIdx.x;
    int tx = t & 15, ty = t >> 4;
    int rowBase = blockIdx.x * 64;
    float acc[4][8] = {};
    for (int kk = 0; kk < 128; kk += 32) {
#pragma unroll
        for (int i = 0; i < 2; ++i) {
            int f4 = t + i * 256;
            int r = f4 >> 3, c = (f4 & 7) * 4;
            int gr = rowBase + r;
            float4 v = make_float4(0.f, 0.f, 0.f, 0.f);
            if (gr < n) v = *(const float4*)&H[gr * 128 + kk + c];
            Hs[r][c + 0] = v.x; Hs[r][c + 1] = v.y;
            Hs[r][c + 2] = v.z; Hs[r][c + 3] = v.w;
        }
#pragma unroll
        for (int i = 0; i < 4; ++i) {
            int f4 = t + i * 256;
            int kr = f4 >> 5, c = (f4 & 31) * 4;
            float4 v = *(const float4*)&W[(kk + kr) * 128 + c];
            *(float4*)&Ws[kr][c] = v;
        }
        __syncthreads();
#pragma unroll
        for (int k = 0; k < 32; ++k) {
            float4 w0 = *(const float4*)&Ws[k][tx * 8];
            float4 w1 = *(const float4*)&Ws[k][tx * 8 + 4];
#pragma unroll
            for (int i = 0; i < 4; ++i) {
                float h = Hs[ty * 4 + i][k];
                acc[i][0] += h * w0.x; acc[i][1] += h * w0.y;
                acc[i][2] += h * w0.z; acc[i][3] += h * w0.w;
                acc[i][4] += h * w1.x; acc[i][5] += h * w1.y;
                acc[i][6] += h * w1.z; acc[i][7] += h * w1.w;
            }
        }
        __syncthreads();
    }
#pragma unroll
    for (int i = 0; i < 4; ++i) {
        int gr = rowBase + ty * 4 + i;
        if (gr < n) {
            ushort8 o;
#pragma unroll
            for (int j = 0; j < 8; ++j) o[j] = f2bf(acc[i][j]);
            *(ushort8*)&O[gr * 128 + tx * 8] = o;
        }
    }
}

// ------- aggregation: out[dst] = sum_e w_e * Hw_bf16[src_e] + b (opt relu), fp32 accum -------
template<bool RELU>
__global__ void k_agg(const unsigned* __restrict__ Hw,   // bf16x2 per uint, 64 uints/row
                      const int* __restrict__ rowptr,
                      const float2* __restrict__ csr,
                      const float* __restrict__ bias, float* __restrict__ out, int n) {
    int node = blockIdx.x * 4 + (threadIdx.x >> 6);
    if (node >= n) return;
    int lane = threadIdx.x & 63;
    int s = rowptr[node], e = rowptr[node + 1];
    float ax = 0.f, ay = 0.f;
    int i = s;
    for (; i + 4 <= e; i += 4) {
        float2 p0 = csr[i + 0], p1 = csr[i + 1], p2 = csr[i + 2], p3 = csr[i + 3];
        unsigned v0 = Hw[__float_as_int(p0.x) * 64 + lane];
        unsigned v1 = Hw[__float_as_int(p1.x) * 64 + lane];
        unsigned v2 = Hw[__float_as_int(p2.x) * 64 + lane];
        unsigned v3 = Hw[__float_as_int(p3.x) * 64 + lane];
        ax += __uint_as_float(v0 << 16) * p0.y;
        ay += __uint_as_float(v0 & 0xFFFF0000u) * p0.y;
        ax += __uint_as_float(v1 << 16) * p1.y;
        ay += __uint_as_float(v1 & 0xFFFF0000u) * p1.y;
        ax += __uint_as_float(v2 << 16) * p2.y;
        ay += __uint_as_float(v2 & 0xFFFF0000u) * p2.y;
        ax += __uint_as_float(v3 << 16) * p3.y;
        ay += __uint_as_float(v3 & 0xFFFF0000u) * p3.y;
    }
    for (; i < e; ++i) {
        float2 p = csr[i];
        unsigned v = Hw[__float_as_int(p.x) * 64 + lane];
        ax += __uint_as_float(v << 16) * p.y;
        ay += __uint_as_float(v & 0xFFFF0000u) * p.y;
    }
    float2 b = *(const float2*)&bias[lane * 2];
    ax += b.x; ay += b.y;
    if (RELU) { ax = fmaxf(ax, 0.f); ay = fmaxf(ay, 0.f); }
    float2 r; r.x = ax; r.y = ay;
    *(float2*)&out[node * 128 + lane * 2] = r;
}

// ---------------- fused mean-pool + final linear ----------------
__device__ __forceinline__ int lower_bound_i(const int* a, int n, int key) {
    int lo = 0, hi = n;
    while (lo < hi) { int mid = (lo + hi) >> 1; if (a[mid] < key) lo = mid + 1; else hi = mid; }
    return lo;
}

__global__ void k_pool(const float* __restrict__ H, const int* __restrict__ batch,
                       const float* __restrict__ Wlin, const float* __restrict__ blin,
                       float* __restrict__ out, int n) {
    int g = blockIdx.x;
    int start = lower_bound_i(batch, n, g);
    int end   = lower_bound_i(batch, n, g + 1);
    int t = threadIdx.x;
    int wid = t >> 6, lane = t & 63;
    float ax = 0.f, ay = 0.f;
    for (int i = start + wid; i < end; i += 4) {
        float2 v = *(const float2*)&H[i * 128 + lane * 2];
        ax += v.x; ay += v.y;
    }
    __shared__ float ws[4][128];
    __shared__ float hg[128];
    ws[wid][lane * 2] = ax; ws[wid][lane * 2 + 1] = ay;
    __syncthreads();
    int cnt = end - start;
    float inv = 1.0f / fmaxf((float)cnt, 1.0f);
    if (t < 128) hg[t] = (ws[0][t] + ws[1][t] + ws[2][t] + ws[3][t]) * inv;
    __syncthreads();
    if (t < 16) {
        float s = blin[t];
        for (int ch = 0; ch < 128; ++ch) s += hg[ch] * Wlin[ch * 16 + t];
        out[g * 16 + t] = s;
    }
}

// ---------------- host ----------------
extern "C" void kernel_launch(void* const* d_in, const int* in_sizes, int n_in,
                              void* d_out, int out_size, void* d_ws, size_t ws_size,
                              hipStream_t stream) {
    const float* x    = (const float*)d_in[0];
    const int*   ei   = (const int*)d_in[1];
    const float* ew   = (const float*)d_in[2];
    const int*   batch= (const int*)d_in[3];
    const float* W1   = (const float*)d_in[4];
    const float* b1   = (const float*)d_in[5];
    const float* W2   = (const float*)d_in[6];
    const float* b2   = (const float*)d_in[7];
    const float* W3   = (const float*)d_in[8];
    const float* b3   = (const float*)d_in[9];
    const float* Wlin = (const float*)d_in[10];
    const float* blin = (const float*)d_in[11];
    float* out = (float*)d_out;

    int n  = in_sizes[0] / 128;
    int E  = in_sizes[2];
    int e2 = E + n;
    int G  = out_size / 16;
    const int* row = ei;
    const int* col = ei + E;

    char* ws = (char*)d_ws;
    size_t off = 0;
    auto alloc = [&](size_t bytes) -> void* {
        void* p = ws + off;
        off = (off + bytes + 255) & ~255UL;
        return p;
    };
    unsigned short* bufHw = (unsigned short*)alloc((size_t)n * 128 * 2);  // bf16 messages
    float* bufF   = (float*)alloc((size_t)n * 128 * 4);                   // fp32 agg output
    float* deg    = (float*)alloc((size_t)n * 4);       // becomes dinv in-place
    int*   cnt    = (int*)  alloc((size_t)n * 4);       // reused as fill counters
    int*   rowptr = (int*)  alloc((size_t)(n + 1) * 4);
    int*   bsum   = (int*)  alloc(4096);
    float2* csr   = (float2*)alloc((size_t)e2 * 8);
    (void)ws_size;

    hipMemsetAsync(deg, 0, (size_t)n * 4, stream);
    hipMemsetAsync(cnt, 0, (size_t)n * 4, stream);

    int eb = (e2 + 255) / 256;
    k_deg_count<<<eb, 256, 0, stream>>>(row, col, ew, E, e2, deg, cnt);
    k_dinv<<<(n + 255) / 256, 256, 0, stream>>>(deg, n);

    int nbScan = (n + SCAN_E - 1) / SCAN_E;
    k_scan_a<<<nbScan, SCAN_T, 0, stream>>>(cnt, n, rowptr, bsum);
    k_scan_b<<<1, 128, 0, stream>>>(bsum, nbScan);
    k_scan_c<<<(n + 255) / 256, 256, 0, stream>>>(rowptr, bsum, n, e2);

    hipMemsetAsync(cnt, 0, (size_t)n * 4, stream);
    k_fill<<<eb, 256, 0, stream>>>(row, col, ew, deg, rowptr, cnt, E, e2, csr);

    int gb = (n + 63) / 64;
    int ab = (n + 3) / 4;
    k_gemm<<<gb, 256, 0, stream>>>(x, W1, bufHw, n);
    k_agg<true><<<ab, 256, 0, stream>>>((const unsigned*)bufHw, rowptr, csr, b1, bufF, n);
    k_gemm<<<gb, 256, 0, stream>>>(bufF, W2, bufHw, n);
    k_agg<true><<<ab, 256, 0, stream>>>((const unsigned*)bufHw, rowptr, csr, b2, bufF, n);
    k_gemm<<<gb, 256, 0, stream>>>(bufF, W3, bufHw, n);
    k_agg<false><<<ab, 256, 0, stream>>>((const unsigned*)bufHw, rowptr, csr, b3, bufF, n);
    k_pool<<<G, 256, 0, stream>>>(bufF, batch, Wlin, blin, out, n);
}

// Round 3
// 524.500 us; speedup vs baseline: 1.8285x; 1.2375x over previous
//
#include <hip/hip_runtime.h>
#include <hip/hip_bf16.h>

#define SLOTS 64

typedef __attribute__((ext_vector_type(8))) unsigned short ushort8;

__device__ __forceinline__ unsigned short f2bf(float f) {
    unsigned u = __float_as_uint(f);
    unsigned r = (u + 0x7FFF + ((u >> 16) & 1)) >> 16;   // RNE
    return (unsigned short)r;
}

// ---------------- padded-bucket fill: 1 atomic per edge ----------------
__global__ void k_fill_pad(const int* __restrict__ row, const int* __restrict__ col,
                           const float* __restrict__ ew, int E, int e2,
                           int* __restrict__ fill, float2* __restrict__ pad,
                           int* __restrict__ ovf_cnt, int4* __restrict__ ovf, int ovf_cap) {
    int e = blockIdx.x * blockDim.x + threadIdx.x;
    if (e >= e2) return;
    int src, dst; float w;
    if (e < E) { src = row[e]; dst = col[e]; w = ew[e]; }
    else       { src = dst = e - E; w = 1.0f; }
    int c = atomicAdd(&fill[dst], 1);
    if (c < SLOTS) {
        pad[(size_t)dst * SLOTS + c] = make_float2(__int_as_float(src), w);
    } else {
        int q = atomicAdd(ovf_cnt, 1);
        if (q < ovf_cap) ovf[q] = make_int4(src, dst, __float_as_int(w), 0);
    }
}

// ---------------- deg from padded buckets: atomic-free streaming ----------------
__global__ __launch_bounds__(256) void k_deg_pad(const int* __restrict__ fill,
                                                 const float2* __restrict__ pad,
                                                 float* __restrict__ deg, int n) {
    int wv = threadIdx.x >> 6, lane = threadIdx.x & 63;
    int node = blockIdx.x * 32 + wv * 8 + (lane >> 3);
    int sl = lane & 7;
    if (node >= n) return;
    int cnt = min(fill[node], SLOTS);
    float s = 0.f;
    for (int j = sl; j < cnt; j += 8) s += pad[(size_t)node * SLOTS + j].y;
    s += __shfl_xor(s, 1); s += __shfl_xor(s, 2); s += __shfl_xor(s, 4);
    if (sl == 0) deg[node] = s;
}

__global__ void k_deg_ovf(const int* __restrict__ ovf_cnt, const int4* __restrict__ ovf,
                          int ovf_cap, float* __restrict__ deg) {
    int m = min(*ovf_cnt, ovf_cap);
    for (int i = blockIdx.x * blockDim.x + threadIdx.x; i < m; i += gridDim.x * blockDim.x) {
        int4 o = ovf[i];
        atomicAdd(&deg[o.y], __int_as_float(o.z));
    }
}

__global__ void k_dinv(float* __restrict__ deg, int n) {
    int i = blockIdx.x * blockDim.x + threadIdx.x;
    if (i >= n) return;
    float d = deg[i];
    deg[i] = (d > 0.0f) ? rsqrtf(d) : 0.0f;
}

// ---------------- exclusive scan (3-kernel hierarchical) over fill counts ----------------
#define SCAN_T 256
#define SCAN_E 1024

__global__ void k_scan_a(const int* __restrict__ cnt, int n,
                         int* __restrict__ rowptr, int* __restrict__ bsum) {
    __shared__ int s[SCAN_T];
    int t = threadIdx.x, b = blockIdx.x;
    int base = b * SCAN_E + t * 4;
    int c0 = (base + 0 < n) ? cnt[base + 0] : 0;
    int c1 = (base + 1 < n) ? cnt[base + 1] : 0;
    int c2 = (base + 2 < n) ? cnt[base + 2] : 0;
    int c3 = (base + 3 < n) ? cnt[base + 3] : 0;
    int tsum = c0 + c1 + c2 + c3;
    s[t] = tsum; __syncthreads();
    for (int off = 1; off < SCAN_T; off <<= 1) {
        int v = (t >= off) ? s[t - off] : 0;
        __syncthreads();
        s[t] += v;
        __syncthreads();
    }
    int excl = s[t] - tsum;
    if (base + 0 < n) rowptr[base + 0] = excl;
    if (base + 1 < n) rowptr[base + 1] = excl + c0;
    if (base + 2 < n) rowptr[base + 2] = excl + c0 + c1;
    if (base + 3 < n) rowptr[base + 3] = excl + c0 + c1 + c2;
    if (t == 0) bsum[b] = s[SCAN_T - 1];
}

__global__ void k_scan_b(int* __restrict__ bsum, int nb) {
    __shared__ int s[128];
    int t = threadIdx.x;
    int v = (t < nb) ? bsum[t] : 0;
    s[t] = v; __syncthreads();
    for (int off = 1; off < 128; off <<= 1) {
        int u = (t >= off) ? s[t - off] : 0;
        __syncthreads();
        s[t] += u;
        __syncthreads();
    }
    if (t < nb) bsum[t] = s[t] - v;   // exclusive
}

__global__ void k_scan_c(int* __restrict__ rowptr, const int* __restrict__ bsum,
                         int n, int total) {
    int i = blockIdx.x * blockDim.x + threadIdx.x;
    if (i < n) rowptr[i] += bsum[i / SCAN_E];
    if (i == 0) rowptr[n] = total;
}

// ---------------- compact + scale: pad -> tight CSR with final edge weights ----------------
__global__ __launch_bounds__(256) void k_compact_scale(const int* __restrict__ fill,
                                                       const float2* __restrict__ pad,
                                                       const int* __restrict__ rowptr,
                                                       const float* __restrict__ dinv,
                                                       float2* __restrict__ csr, int n) {
    int wv = threadIdx.x >> 6, lane = threadIdx.x & 63;
    int node = blockIdx.x * 32 + wv * 8 + (lane >> 3);
    int sl = lane & 7;
    if (node >= n) return;
    int cnt = min(fill[node], SLOTS);
    int base = rowptr[node];
    float dn = dinv[node];
    for (int j = sl; j < cnt; j += 8) {
        float2 pr = pad[(size_t)node * SLOTS + j];
        int src = __float_as_int(pr.x);
        csr[base + j] = make_float2(pr.x, dinv[src] * pr.y * dn);
    }
}

__global__ void k_ovf_place(const int* __restrict__ ovf_cnt, const int4* __restrict__ ovf,
                            int ovf_cap, const int* __restrict__ rowptr,
                            const float* __restrict__ dinv, int* __restrict__ fill2,
                            float2* __restrict__ csr) {
    int m = min(*ovf_cnt, ovf_cap);
    for (int i = blockIdx.x * blockDim.x + threadIdx.x; i < m; i += gridDim.x * blockDim.x) {
        int4 o = ovf[i];
        int p = rowptr[o.y] + SLOTS + atomicAdd(&fill2[o.y], 1);
        csr[p] = make_float2(__int_as_float(o.x), dinv[o.x] * __int_as_float(o.z) * dinv[o.y]);
    }
}

// ---------------- fp32 GEMM -> bf16 out: O[n x 128] = H[n x 128] @ W[128 x 128] ----------------
__global__ __launch_bounds__(256) void k_gemm(const float* __restrict__ H,
                                              const float* __restrict__ W,
                                              unsigned short* __restrict__ O, int n) {
    __shared__ float Hs[64][33];
    __shared__ float Ws[32][132];
    int t = threadIdx.x;
    int tx = t & 15, ty = t >> 4;
    int rowBase = blockIdx.x * 64;
    float acc[4][8] = {};
    for (int kk = 0; kk < 128; kk += 32) {
#pragma unroll
        for (int i = 0; i < 2; ++i) {
            int f4 = t + i * 256;
            int r = f4 >> 3, c = (f4 & 7) * 4;
            int gr = rowBase + r;
            float4 v = make_float4(0.f, 0.f, 0.f, 0.f);
            if (gr < n) v = *(const float4*)&H[gr * 128 + kk + c];
            Hs[r][c + 0] = v.x; Hs[r][c + 1] = v.y;
            Hs[r][c + 2] = v.z; Hs[r][c + 3] = v.w;
        }
#pragma unroll
        for (int i = 0; i < 4; ++i) {
            int f4 = t + i * 256;
            int kr = f4 >> 5, c = (f4 & 31) * 4;
            float4 v = *(const float4*)&W[(kk + kr) * 128 + c];
            *(float4*)&Ws[kr][c] = v;
        }
        __syncthreads();
#pragma unroll
        for (int k = 0; k < 32; ++k) {
            float4 w0 = *(const float4*)&Ws[k][tx * 8];
            float4 w1 = *(const float4*)&Ws[k][tx * 8 + 4];
#pragma unroll
            for (int i = 0; i < 4; ++i) {
                float h = Hs[ty * 4 + i][k];
                acc[i][0] += h * w0.x; acc[i][1] += h * w0.y;
                acc[i][2] += h * w0.z; acc[i][3] += h * w0.w;
                acc[i][4] += h * w1.x; acc[i][5] += h * w1.y;
                acc[i][6] += h * w1.z; acc[i][7] += h * w1.w;
            }
        }
        __syncthreads();
    }
#pragma unroll
    for (int i = 0; i < 4; ++i) {
        int gr = rowBase + ty * 4 + i;
        if (gr < n) {
            ushort8 o;
#pragma unroll
            for (int j = 0; j < 8; ++j) o[j] = f2bf(acc[i][j]);
            *(ushort8*)&O[gr * 128 + tx * 8] = o;
        }
    }
}

// ------- aggregation: 16 lanes/node, 4 nodes/wave, dwordx4 gathers, fp32 accum -------
template<bool RELU>
__global__ __launch_bounds__(256) void k_agg(const uint4* __restrict__ Hw,   // 16 x 16B chunks/row
                                             const int* __restrict__ rowptr,
                                             const float2* __restrict__ csr,
                                             const float* __restrict__ bias,
                                             float* __restrict__ out, int n) {
    int wv = threadIdx.x >> 6, lane = threadIdx.x & 63;
    int g = lane >> 4, sl = lane & 15;
    int node = blockIdx.x * 16 + wv * 4 + g;
    bool act = node < n;
    int s = 0, e = 0;
    if (act) { s = rowptr[node]; e = rowptr[node + 1]; }
    float a0 = 0.f, a1 = 0.f, a2 = 0.f, a3 = 0.f, a4 = 0.f, a5 = 0.f, a6 = 0.f, a7 = 0.f;

#define FMA8(V, W8) do {                                              \
    float _w = (W8);                                                  \
    a0 += __uint_as_float((V).x << 16) * _w;                          \
    a1 += __uint_as_float((V).x & 0xFFFF0000u) * _w;                  \
    a2 += __uint_as_float((V).y << 16) * _w;                          \
    a3 += __uint_as_float((V).y & 0xFFFF0000u) * _w;                  \
    a4 += __uint_as_float((V).z << 16) * _w;                          \
    a5 += __uint_as_float((V).z & 0xFFFF0000u) * _w;                  \
    a6 += __uint_as_float((V).w << 16) * _w;                          \
    a7 += __uint_as_float((V).w & 0xFFFF0000u) * _w;                  \
} while (0)

    int i = s;
    for (; i + 4 <= e; i += 4) {
        float2 p0 = csr[i + 0], p1 = csr[i + 1], p2 = csr[i + 2], p3 = csr[i + 3];
        uint4 v0 = Hw[(size_t)__float_as_int(p0.x) * 16 + sl];
        uint4 v1 = Hw[(size_t)__float_as_int(p1.x) * 16 + sl];
        uint4 v2 = Hw[(size_t)__float_as_int(p2.x) * 16 + sl];
        uint4 v3 = Hw[(size_t)__float_as_int(p3.x) * 16 + sl];
        FMA8(v0, p0.y); FMA8(v1, p1.y); FMA8(v2, p2.y); FMA8(v3, p3.y);
    }
    for (; i < e; ++i) {
        float2 p = csr[i];
        uint4 v = Hw[(size_t)__float_as_int(p.x) * 16 + sl];
        FMA8(v, p.y);
    }
#undef FMA8

    if (act) {
        const float4* b4 = (const float4*)&bias[sl * 8];
        float4 b0 = b4[0], b1 = b4[1];
        a0 += b0.x; a1 += b0.y; a2 += b0.z; a3 += b0.w;
        a4 += b1.x; a5 += b1.y; a6 += b1.z; a7 += b1.w;
        if (RELU) {
            a0 = fmaxf(a0, 0.f); a1 = fmaxf(a1, 0.f); a2 = fmaxf(a2, 0.f); a3 = fmaxf(a3, 0.f);
            a4 = fmaxf(a4, 0.f); a5 = fmaxf(a5, 0.f); a6 = fmaxf(a6, 0.f); a7 = fmaxf(a7, 0.f);
        }
        float4* o4 = (float4*)&out[(size_t)node * 128 + sl * 8];
        o4[0] = make_float4(a0, a1, a2, a3);
        o4[1] = make_float4(a4, a5, a6, a7);
    }
}

// ---------------- fused mean-pool + final linear ----------------
__device__ __forceinline__ int lower_bound_i(const int* a, int n, int key) {
    int lo = 0, hi = n;
    while (lo < hi) { int mid = (lo + hi) >> 1; if (a[mid] < key) lo = mid + 1; else hi = mid; }
    return lo;
}

__global__ void k_pool(const float* __restrict__ H, const int* __restrict__ batch,
                       const float* __restrict__ Wlin, const float* __restrict__ blin,
                       float* __restrict__ out, int n) {
    int g = blockIdx.x;
    int start = lower_bound_i(batch, n, g);
    int end   = lower_bound_i(batch, n, g + 1);
    int t = threadIdx.x;
    int wid = t >> 6, lane = t & 63;
    float ax = 0.f, ay = 0.f;
    for (int i = start + wid; i < end; i += 4) {
        float2 v = *(const float2*)&H[(size_t)i * 128 + lane * 2];
        ax += v.x; ay += v.y;
    }
    __shared__ float ws[4][128];
    __shared__ float hg[128];
    ws[wid][lane * 2] = ax; ws[wid][lane * 2 + 1] = ay;
    __syncthreads();
    int cnt = end - start;
    float inv = 1.0f / fmaxf((float)cnt, 1.0f);
    if (t < 128) hg[t] = (ws[0][t] + ws[1][t] + ws[2][t] + ws[3][t]) * inv;
    __syncthreads();
    if (t < 16) {
        float s = blin[t];
        for (int ch = 0; ch < 128; ++ch) s += hg[ch] * Wlin[ch * 16 + t];
        out[g * 16 + t] = s;
    }
}

// ---------------- host ----------------
extern "C" void kernel_launch(void* const* d_in, const int* in_sizes, int n_in,
                              void* d_out, int out_size, void* d_ws, size_t ws_size,
                              hipStream_t stream) {
    const float* x    = (const float*)d_in[0];
    const int*   ei   = (const int*)d_in[1];
    const float* ew   = (const float*)d_in[2];
    const int*   batch= (const int*)d_in[3];
    const float* W1   = (const float*)d_in[4];
    const float* b1   = (const float*)d_in[5];
    const float* W2   = (const float*)d_in[6];
    const float* b2   = (const float*)d_in[7];
    const float* W3   = (const float*)d_in[8];
    const float* b3   = (const float*)d_in[9];
    const float* Wlin = (const float*)d_in[10];
    const float* blin = (const float*)d_in[11];
    float* out = (float*)d_out;

    int n  = in_sizes[0] / 128;
    int E  = in_sizes[2];
    int e2 = E + n;
    int G  = out_size / 16;
    const int* row = ei;
    const int* col = ei + E;

    char* ws = (char*)d_ws;
    size_t off = 0;
    auto alloc = [&](size_t bytes) -> void* {
        void* p = ws + off;
        off = (off + bytes + 255) & ~255UL;
        return p;
    };
    // region A: padded buckets (n*SLOTS*8B) early, fp32 agg output (n*128*4B) later
    size_t padBytes = (size_t)n * SLOTS * 8;
    size_t bufBytes = (size_t)n * 128 * 4;
    void* regionA = alloc(padBytes > bufBytes ? padBytes : bufBytes);
    float2* pad  = (float2*)regionA;
    float*  bufF = (float*)regionA;
    unsigned short* bufHw = (unsigned short*)alloc((size_t)n * 128 * 2);  // bf16 messages
    float2* csr   = (float2*)alloc((size_t)e2 * 8);
    float*  deg   = (float*)alloc((size_t)n * 4);       // becomes dinv in-place
    int*    fill  = (int*)  alloc((size_t)n * 4);
    int*    fill2 = (int*)  alloc((size_t)n * 4);
    int*    rowptr= (int*)  alloc((size_t)(n + 1) * 4);
    int*    bsum  = (int*)  alloc(4096);
    int*    ovf_cnt = (int*)alloc(256);
    const int ovf_cap = 131072;
    int4*   ovf   = (int4*) alloc((size_t)ovf_cap * 16);
    (void)ws_size;

    hipMemsetAsync(fill, 0, (size_t)n * 4, stream);
    hipMemsetAsync(fill2, 0, (size_t)n * 4, stream);
    hipMemsetAsync(ovf_cnt, 0, 4, stream);

    int eb = (e2 + 255) / 256;
    k_fill_pad<<<eb, 256, 0, stream>>>(row, col, ew, E, e2, fill, pad, ovf_cnt, ovf, ovf_cap);

    int nb32 = (n + 31) / 32;
    k_deg_pad<<<nb32, 256, 0, stream>>>(fill, pad, deg, n);
    k_deg_ovf<<<32, 256, 0, stream>>>(ovf_cnt, ovf, ovf_cap, deg);
    k_dinv<<<(n + 255) / 256, 256, 0, stream>>>(deg, n);

    int nbScan = (n + SCAN_E - 1) / SCAN_E;
    k_scan_a<<<nbScan, SCAN_T, 0, stream>>>(fill, n, rowptr, bsum);
    k_scan_b<<<1, 128, 0, stream>>>(bsum, nbScan);
    k_scan_c<<<(n + 255) / 256, 256, 0, stream>>>(rowptr, bsum, n, e2);

    k_compact_scale<<<nb32, 256, 0, stream>>>(fill, pad, rowptr, deg, csr, n);
    k_ovf_place<<<32, 256, 0, stream>>>(ovf_cnt, ovf, ovf_cap, rowptr, deg, fill2, csr);

    int gb = (n + 63) / 64;
    int ab = (n + 15) / 16;
    k_gemm<<<gb, 256, 0, stream>>>(x, W1, bufHw, n);
    k_agg<true><<<ab, 256, 0, stream>>>((const uint4*)bufHw, rowptr, csr, b1, bufF, n);
    k_gemm<<<gb, 256, 0, stream>>>(bufF, W2, bufHw, n);
    k_agg<true><<<ab, 256, 0, stream>>>((const uint4*)bufHw, rowptr, csr, b2, bufF, n);
    k_gemm<<<gb, 256, 0, stream>>>(bufF, W3, bufHw, n);
    k_agg<false><<<ab, 256, 0, stream>>>((const uint4*)bufHw, rowptr, csr, b3, bufF, n);
    k_pool<<<G, 256, 0, stream>>>(bufF, batch, Wlin, blin, out, n);
}

// Round 4
// 433.407 us; speedup vs baseline: 2.2128x; 1.2102x over previous
//
#include <hip/hip_runtime.h>
#include <hip/hip_bf16.h>

#define NB 256          // edge-pass blocks
#define MAXBKT 512      // supports n <= 131072

typedef __attribute__((ext_vector_type(8))) unsigned short ushort8;

__device__ __forceinline__ unsigned short f2bf(float f) {
    unsigned u = __float_as_uint(f);
    unsigned r = (u + 0x7FFF + ((u >> 16) & 1)) >> 16;   // RNE
    return (unsigned short)r;
}

// ---- pass 1: per-(bucket,block) histogram of dst>>8 (zero global atomics) ----
__global__ __launch_bounds__(256) void k_hist1(const int* __restrict__ col, int E, int e2,
                                               int per, int* __restrict__ cnt, int nbkt) {
    __shared__ int h[MAXBKT];
    int t = threadIdx.x;
    for (int i = t; i < nbkt; i += 256) h[i] = 0;
    __syncthreads();
    int s = blockIdx.x * per, e = min(s + per, e2);
    for (int i = s + t; i < e; i += 256) {
        int dst = (i < E) ? col[i] : i - E;
        atomicAdd(&h[dst >> 8], 1);
    }
    __syncthreads();
    for (int i = t; i < nbkt; i += 256) cnt[i * NB + blockIdx.x] = h[i];
}

// ---- hierarchical exclusive scan ----
#define SCAN_T 256
#define SCAN_E 1024

__global__ void k_scan_a(const int* __restrict__ cnt, int n,
                         int* __restrict__ outp, int* __restrict__ bsum) {
    __shared__ int s[SCAN_T];
    int t = threadIdx.x, b = blockIdx.x;
    int base = b * SCAN_E + t * 4;
    int c0 = (base + 0 < n) ? cnt[base + 0] : 0;
    int c1 = (base + 1 < n) ? cnt[base + 1] : 0;
    int c2 = (base + 2 < n) ? cnt[base + 2] : 0;
    int c3 = (base + 3 < n) ? cnt[base + 3] : 0;
    int tsum = c0 + c1 + c2 + c3;
    s[t] = tsum; __syncthreads();
    for (int off = 1; off < SCAN_T; off <<= 1) {
        int v = (t >= off) ? s[t - off] : 0;
        __syncthreads();
        s[t] += v;
        __syncthreads();
    }
    int excl = s[t] - tsum;
    if (base + 0 < n) outp[base + 0] = excl;
    if (base + 1 < n) outp[base + 1] = excl + c0;
    if (base + 2 < n) outp[base + 2] = excl + c0 + c1;
    if (base + 3 < n) outp[base + 3] = excl + c0 + c1 + c2;
    if (t == 0) bsum[b] = s[SCAN_T - 1];
}

__global__ void k_scan_b(int* __restrict__ bsum, int nb) {
    __shared__ int s[128];
    int t = threadIdx.x;
    int v = (t < nb) ? bsum[t] : 0;
    s[t] = v; __syncthreads();
    for (int off = 1; off < 128; off <<= 1) {
        int u = (t >= off) ? s[t - off] : 0;
        __syncthreads();
        s[t] += u;
        __syncthreads();
    }
    if (t < nb) bsum[t] = s[t] - v;   // exclusive
}

__global__ void k_scan_c(int* __restrict__ outp, const int* __restrict__ bsum,
                         int n, int total) {
    int i = blockIdx.x * blockDim.x + threadIdx.x;
    if (i < n) outp[i] += bsum[i / SCAN_E];
    if (i == 0) outp[n] = total;
}

// ---- pass 3: scatter edges to exact bucket-major slots (zero global atomics) ----
__global__ __launch_bounds__(256) void k_scatter1(const int* __restrict__ row,
                                                  const int* __restrict__ col,
                                                  const float* __restrict__ ew,
                                                  int E, int e2, int per,
                                                  const int* __restrict__ S,
                                                  uint2* __restrict__ csrR, int nbkt) {
    __shared__ int cur[MAXBKT];
    int t = threadIdx.x;
    for (int i = t; i < nbkt; i += 256) cur[i] = S[i * NB + blockIdx.x];
    __syncthreads();
    int s = blockIdx.x * per, e = min(s + per, e2);
    for (int i = s + t; i < e; i += 256) {
        int src, dst; float w;
        if (i < E) { src = row[i]; dst = col[i]; w = ew[i]; }
        else       { src = dst = i - E; w = 1.0f; }
        int slot = atomicAdd(&cur[dst >> 8], 1);
        csrR[slot] = make_uint2(((unsigned)src << 8) | (unsigned)(dst & 255),
                                __float_as_uint(w));
    }
}

// ---- pass 4: per-bucket regroup by dst; emits dinv, rowptr, final CSR ----
__global__ __launch_bounds__(256) void k_build(const uint2* __restrict__ csrR,
                                               const int* __restrict__ S,
                                               int n, int e2,
                                               float2* __restrict__ csrF,
                                               float* __restrict__ dinv,
                                               int* __restrict__ rowptr, int nbkt) {
    __shared__ int   cnt[256];
    __shared__ float wsm[256];
    __shared__ int   off[256];
    __shared__ float dvs[256];
    __shared__ int   curs[256];
    int b = blockIdx.x, t = threadIdx.x;
    cnt[t] = 0; wsm[t] = 0.f;
    __syncthreads();
    int base = S[b * NB], end = S[(b + 1) * NB];   // S[nbkt*NB] == e2
    for (int i = base + t; i < end; i += 256) {
        uint2 r = csrR[i];
        int d = r.x & 255;
        atomicAdd(&cnt[d], 1);
        atomicAdd(&wsm[d], __uint_as_float(r.y));
    }
    __syncthreads();
    int   myc = cnt[t];
    float w   = wsm[t];
    float dv  = (w > 0.f) ? rsqrtf(w) : 0.f;
    dvs[t] = dv;
    off[t] = myc;
    __syncthreads();
    for (int o = 1; o < 256; o <<= 1) {
        int v = (t >= o) ? off[t - o] : 0;
        __syncthreads();
        off[t] += v;
        __syncthreads();
    }
    int excl = off[t] - myc;
    int node = b * 256 + t;
    if (node < n) { dinv[node] = dv; rowptr[node] = base + excl; }
    if (b == nbkt - 1 && t == 0) rowptr[n] = e2;
    curs[t] = excl;
    __syncthreads();
    for (int i = base + t; i < end; i += 256) {
        uint2 r = csrR[i];
        int d = r.x & 255;
        int src = (int)(r.x >> 8);
        int p = base + atomicAdd(&curs[d], 1);
        csrF[p] = make_float2(__int_as_float(src), __uint_as_float(r.y) * dvs[d]);
    }
}

// ---- fp32 GEMM -> bf16 out, row-scaled by dinv: O[r] = bf16((H@W)[r] * dinv[r]) ----
__global__ __launch_bounds__(256) void k_gemm(const float* __restrict__ H,
                                              const float* __restrict__ W,
                                              const float* __restrict__ dinv,
                                              unsigned short* __restrict__ O, int n) {
    __shared__ float Hs[64][33];
    __shared__ float Ws[32][132];
    int t = threadIdx.x;
    int tx = t & 15, ty = t >> 4;
    int rowBase = blockIdx.x * 64;
    float acc[4][8] = {};
    for (int kk = 0; kk < 128; kk += 32) {
#pragma unroll
        for (int i = 0; i < 2; ++i) {
            int f4 = t + i * 256;
            int r = f4 >> 3, c = (f4 & 7) * 4;
            int gr = rowBase + r;
            float4 v = make_float4(0.f, 0.f, 0.f, 0.f);
            if (gr < n) v = *(const float4*)&H[(size_t)gr * 128 + kk + c];
            Hs[r][c + 0] = v.x; Hs[r][c + 1] = v.y;
            Hs[r][c + 2] = v.z; Hs[r][c + 3] = v.w;
        }
#pragma unroll
        for (int i = 0; i < 4; ++i) {
            int f4 = t + i * 256;
            int kr = f4 >> 5, c = (f4 & 31) * 4;
            float4 v = *(const float4*)&W[(kk + kr) * 128 + c];
            *(float4*)&Ws[kr][c] = v;
        }
        __syncthreads();
#pragma unroll
        for (int k = 0; k < 32; ++k) {
            float4 w0 = *(const float4*)&Ws[k][tx * 8];
            float4 w1 = *(const float4*)&Ws[k][tx * 8 + 4];
#pragma unroll
            for (int i = 0; i < 4; ++i) {
                float h = Hs[ty * 4 + i][k];
                acc[i][0] += h * w0.x; acc[i][1] += h * w0.y;
                acc[i][2] += h * w0.z; acc[i][3] += h * w0.w;
                acc[i][4] += h * w1.x; acc[i][5] += h * w1.y;
                acc[i][6] += h * w1.z; acc[i][7] += h * w1.w;
            }
        }
        __syncthreads();
    }
#pragma unroll
    for (int i = 0; i < 4; ++i) {
        int gr = rowBase + ty * 4 + i;
        if (gr < n) {
            float sc = dinv[gr];
            ushort8 o;
#pragma unroll
            for (int j = 0; j < 8; ++j) o[j] = f2bf(acc[i][j] * sc);
            *(ushort8*)&O[(size_t)gr * 128 + tx * 8] = o;
        }
    }
}

// ------- aggregation: 16 lanes/node, 4 nodes/wave, dwordx4 gathers, fp32 accum -------
template<bool RELU>
__global__ __launch_bounds__(256) void k_agg(const uint4* __restrict__ Hw,
                                             const int* __restrict__ rowptr,
                                             const float2* __restrict__ csr,
                                             const float* __restrict__ bias,
                                             float* __restrict__ out, int n) {
    int wv = threadIdx.x >> 6, lane = threadIdx.x & 63;
    int g = lane >> 4, sl = lane & 15;
    int node = blockIdx.x * 16 + wv * 4 + g;
    bool act = node < n;
    int s = 0, e = 0;
    if (act) { s = rowptr[node]; e = rowptr[node + 1]; }
    float a0 = 0.f, a1 = 0.f, a2 = 0.f, a3 = 0.f, a4 = 0.f, a5 = 0.f, a6 = 0.f, a7 = 0.f;

#define FMA8(V, W8) do {                                              \
    float _w = (W8);                                                  \
    a0 += __uint_as_float((V).x << 16) * _w;                          \
    a1 += __uint_as_float((V).x & 0xFFFF0000u) * _w;                  \
    a2 += __uint_as_float((V).y << 16) * _w;                          \
    a3 += __uint_as_float((V).y & 0xFFFF0000u) * _w;                  \
    a4 += __uint_as_float((V).z << 16) * _w;                          \
    a5 += __uint_as_float((V).z & 0xFFFF0000u) * _w;                  \
    a6 += __uint_as_float((V).w << 16) * _w;                          \
    a7 += __uint_as_float((V).w & 0xFFFF0000u) * _w;                  \
} while (0)

    int i = s;
    for (; i + 4 <= e; i += 4) {
        float2 p0 = csr[i + 0], p1 = csr[i + 1], p2 = csr[i + 2], p3 = csr[i + 3];
        uint4 v0 = Hw[(size_t)__float_as_int(p0.x) * 16 + sl];
        uint4 v1 = Hw[(size_t)__float_as_int(p1.x) * 16 + sl];
        uint4 v2 = Hw[(size_t)__float_as_int(p2.x) * 16 + sl];
        uint4 v3 = Hw[(size_t)__float_as_int(p3.x) * 16 + sl];
        FMA8(v0, p0.y); FMA8(v1, p1.y); FMA8(v2, p2.y); FMA8(v3, p3.y);
    }
    for (; i < e; ++i) {
        float2 p = csr[i];
        uint4 v = Hw[(size_t)__float_as_int(p.x) * 16 + sl];
        FMA8(v, p.y);
    }
#undef FMA8

    if (act) {
        const float4* b4 = (const float4*)&bias[sl * 8];
        float4 b0 = b4[0], b1 = b4[1];
        a0 += b0.x; a1 += b0.y; a2 += b0.z; a3 += b0.w;
        a4 += b1.x; a5 += b1.y; a6 += b1.z; a7 += b1.w;
        if (RELU) {
            a0 = fmaxf(a0, 0.f); a1 = fmaxf(a1, 0.f); a2 = fmaxf(a2, 0.f); a3 = fmaxf(a3, 0.f);
            a4 = fmaxf(a4, 0.f); a5 = fmaxf(a5, 0.f); a6 = fmaxf(a6, 0.f); a7 = fmaxf(a7, 0.f);
        }
        float4* o4 = (float4*)&out[(size_t)node * 128 + sl * 8];
        o4[0] = make_float4(a0, a1, a2, a3);
        o4[1] = make_float4(a4, a5, a6, a7);
    }
}

// ---------------- fused mean-pool + final linear ----------------
__device__ __forceinline__ int lower_bound_i(const int* a, int n, int key) {
    int lo = 0, hi = n;
    while (lo < hi) { int mid = (lo + hi) >> 1; if (a[mid] < key) lo = mid + 1; else hi = mid; }
    return lo;
}

__global__ void k_pool(const float* __restrict__ H, const int* __restrict__ batch,
                       const float* __restrict__ Wlin, const float* __restrict__ blin,
                       float* __restrict__ out, int n) {
    int g = blockIdx.x;
    int start = lower_bound_i(batch, n, g);
    int end   = lower_bound_i(batch, n, g + 1);
    int t = threadIdx.x;
    int wid = t >> 6, lane = t & 63;
    float ax = 0.f, ay = 0.f;
    for (int i = start + wid; i < end; i += 4) {
        float2 v = *(const float2*)&H[(size_t)i * 128 + lane * 2];
        ax += v.x; ay += v.y;
    }
    __shared__ float ws[4][128];
    __shared__ float hg[128];
    ws[wid][lane * 2] = ax; ws[wid][lane * 2 + 1] = ay;
    __syncthreads();
    int cnt = end - start;
    float inv = 1.0f / fmaxf((float)cnt, 1.0f);
    if (t < 128) hg[t] = (ws[0][t] + ws[1][t] + ws[2][t] + ws[3][t]) * inv;
    __syncthreads();
    if (t < 16) {
        float s = blin[t];
        for (int ch = 0; ch < 128; ++ch) s += hg[ch] * Wlin[ch * 16 + t];
        out[g * 16 + t] = s;
    }
}

// ---------------- host ----------------
extern "C" void kernel_launch(void* const* d_in, const int* in_sizes, int n_in,
                              void* d_out, int out_size, void* d_ws, size_t ws_size,
                              hipStream_t stream) {
    const float* x    = (const float*)d_in[0];
    const int*   ei   = (const int*)d_in[1];
    const float* ew   = (const float*)d_in[2];
    const int*   batch= (const int*)d_in[3];
    const float* W1   = (const float*)d_in[4];
    const float* b1   = (const float*)d_in[5];
    const float* W2   = (const float*)d_in[6];
    const float* b2   = (const float*)d_in[7];
    const float* W3   = (const float*)d_in[8];
    const float* b3   = (const float*)d_in[9];
    const float* Wlin = (const float*)d_in[10];
    const float* blin = (const float*)d_in[11];
    float* out = (float*)d_out;

    int n  = in_sizes[0] / 128;
    int E  = in_sizes[2];
    int e2 = E + n;
    int G  = out_size / 16;
    const int* row = ei;
    const int* col = ei + E;

    int nbkt = (n + 255) >> 8;          // 256 nodes per bucket
    int M    = nbkt * NB;               // per-(bucket,block) count grid

    char* ws = (char*)d_ws;
    size_t off = 0;
    auto alloc = [&](size_t bytes) -> void* {
        void* p = ws + off;
        off = (off + bytes + 255) & ~255UL;
        return p;
    };
    // region A: raw bucketed records (e2*8B) early, fp32 agg output (n*128*4B) later
    size_t rawBytes = (size_t)e2 * 8;
    size_t bufBytes = (size_t)n * 128 * 4;
    void* regionA = alloc(rawBytes > bufBytes ? rawBytes : bufBytes);
    uint2*  csrR  = (uint2*)regionA;
    float*  bufF  = (float*)regionA;
    unsigned short* bufHw = (unsigned short*)alloc((size_t)n * 128 * 2);
    float2* csrF  = (float2*)alloc((size_t)e2 * 8);
    int*    cntA  = (int*)  alloc((size_t)M * 4);
    int*    S     = (int*)  alloc((size_t)(M + 1) * 4);
    int*    bsum  = (int*)  alloc(4096);
    float*  dinv  = (float*)alloc((size_t)n * 4);
    int*    rowptr= (int*)  alloc((size_t)(n + 1) * 4);
    (void)ws_size;

    int per = (e2 + NB - 1) / NB;
    k_hist1<<<NB, 256, 0, stream>>>(col, E, e2, per, cntA, nbkt);

    int nbScan = (M + SCAN_E - 1) / SCAN_E;
    k_scan_a<<<nbScan, SCAN_T, 0, stream>>>(cntA, M, S, bsum);
    k_scan_b<<<1, 128, 0, stream>>>(bsum, nbScan);
    k_scan_c<<<(M + 255) / 256, 256, 0, stream>>>(S, bsum, M, e2);

    k_scatter1<<<NB, 256, 0, stream>>>(row, col, ew, E, e2, per, S, csrR, nbkt);
    k_build<<<nbkt, 256, 0, stream>>>(csrR, S, n, e2, csrF, dinv, rowptr, nbkt);

    int gb = (n + 63) / 64;
    int ab = (n + 15) / 16;
    k_gemm<<<gb, 256, 0, stream>>>(x, W1, dinv, bufHw, n);
    k_agg<true><<<ab, 256, 0, stream>>>((const uint4*)bufHw, rowptr, csrF, b1, bufF, n);
    k_gemm<<<gb, 256, 0, stream>>>(bufF, W2, dinv, bufHw, n);
    k_agg<true><<<ab, 256, 0, stream>>>((const uint4*)bufHw, rowptr, csrF, b2, bufF, n);
    k_gemm<<<gb, 256, 0, stream>>>(bufF, W3, dinv, bufHw, n);
    k_agg<false><<<ab, 256, 0, stream>>>((const uint4*)bufHw, rowptr, csrF, b3, bufF, n);
    k_pool<<<G, 256, 0, stream>>>(bufF, batch, Wlin, blin, out, n);
}